// Round 11
// baseline (164.150 us; speedup 1.0000x reference)
//
#include <hip/hip_runtime.h>
#include <hip/hip_fp16.h>

#define LDIM 256
#define NDIM 256
#define DZC  128
#define HN   4
#define DHD  32
#define DCC  128
#define MROWS (LDIM*NDIM)

typedef _Float16 f16;
typedef _Float16 f16x2 __attribute__((ext_vector_type(2)));
typedef _Float16 f16x4 __attribute__((ext_vector_type(4)));
typedef _Float16 f16x8 __attribute__((ext_vector_type(8)));
typedef __fp16   h16x2 __attribute__((ext_vector_type(2)));
typedef float    f32x4 __attribute__((ext_vector_type(4)));

#define SCAL 0.17677669529663687f      // 1/sqrt(32)
#define CEXP -0.011270992135622957f    // -log2(e)/128
#define CPRE 0.2550340490960039f       // SCAL * log2(e)

__device__ inline f16x2 pkrtz(float a, float b){
  h16x2 r = __builtin_amdgcn_cvt_pkrtz(a, b);
  union { h16x2 h; f16x2 f; } u; u.h = r;
  return u.f;
}

// ---------------- K0b: pack W^T f16 — w16[p][col][k] = W_p[k][col] ----------------
__global__ __launch_bounds__(256) void k0b_pack(
    const float* __restrict__ Wq, const float* __restrict__ Wk,
    const float* __restrict__ Wv, const float* __restrict__ Wg,
    const float* __restrict__ Wo, f16* __restrict__ w16)
{
  const float* Ws[5] = {Wq, Wk, Wv, Wg, Wo};
  const int tid = blockIdx.x * 256 + threadIdx.x;
  const int p = tid >> 14, rem = tid & 16383;
  const int col = rem >> 7, k = rem & 127;
  w16[tid] = (f16)Ws[p][k*128 + col];
}

// ---------------- K1: LN + Q/K/V/Gate via MFMA ----------------
__global__ __launch_bounds__(256, 2) void k1_ln_qkvg(
    const float* __restrict__ z, const float* __restrict__ lng, const float* __restrict__ lnb,
    const f16* __restrict__ w16,
    const float* __restrict__ bq, const float* __restrict__ bk,
    const float* __restrict__ bv, const float* __restrict__ bg,
    f16* __restrict__ qb, f16* __restrict__ kbuf,
    f16* __restrict__ vbuf, f16* __restrict__ gateb)
{
  __shared__ f16 zl[64*128];   // 16 KB
  const int t = threadIdx.x;
  const int w = t >> 6, lane = t & 63;
  const int m = lane & 15, g = lane >> 4;
  const int row0 = blockIdx.x * 64;

  {
    const int r = t >> 2, part = t & 3;
    const float* zr = z + (size_t)(row0 + r)*DZC + part*32;
    float vals[32];
    float s = 0.f, sq = 0.f;
    #pragma unroll
    for (int i = 0; i < 8; ++i) {
      float4 v4 = reinterpret_cast<const float4*>(zr)[i];
      vals[i*4+0]=v4.x; vals[i*4+1]=v4.y; vals[i*4+2]=v4.z; vals[i*4+3]=v4.w;
      s  += v4.x+v4.y+v4.z+v4.w;
      sq += v4.x*v4.x + v4.y*v4.y + v4.z*v4.z + v4.w*v4.w;
    }
    s  += __shfl_xor(s, 1);  sq += __shfl_xor(sq, 1);
    s  += __shfl_xor(s, 2);  sq += __shfl_xor(sq, 2);
    const float mu  = s * (1.f/DZC);
    const float var = sq * (1.f/DZC) - mu*mu;
    const float rstd = rsqrtf(var + 1e-5f);
    const float* gg = lng + part*32;
    const float* bb = lnb + part*32;
    #pragma unroll
    for (int i = 0; i < 4; ++i) {
      f16x8 o;
      #pragma unroll
      for (int e = 0; e < 8; ++e)
        o[e] = (f16)((vals[i*8+e]-mu)*rstd*gg[i*8+e] + bb[i*8+e]);
      *reinterpret_cast<f16x8*>(zl + r*128 + (((part*4+i) ^ (r&7))*8)) = o;
    }
  }
  __syncthreads();

  const f16* wp = w16 + w*16384;
  f32x4 acc[4][8];
  #pragma unroll
  for (int it=0;it<4;++it)
    #pragma unroll
    for (int jt=0;jt<8;++jt) acc[it][jt] = (f32x4){0.f,0.f,0.f,0.f};

  #pragma unroll
  for (int ks = 0; ks < 4; ++ks) {
    f16x8 af[8];
    #pragma unroll
    for (int jt=0;jt<8;++jt)
      af[jt] = *reinterpret_cast<const f16x8*>(wp + (jt*16+m)*128 + ks*32 + g*8);
    f16x8 bf[4];
    #pragma unroll
    for (int it=0;it<4;++it)
      bf[it] = *reinterpret_cast<const f16x8*>(zl + (it*16+m)*128 + (((ks*4+g) ^ (m&7))*8));
    #pragma unroll
    for (int it=0;it<4;++it)
      #pragma unroll
      for (int jt=0;jt<8;++jt)
        acc[it][jt] = __builtin_amdgcn_mfma_f32_16x16x32_f16(af[jt], bf[it], acc[it][jt], 0,0,0);
  }

  const float* bsp = (w==0) ? bq : (w==1) ? bk : (w==2) ? bv : bg;
  float4 bias[8];
  #pragma unroll
  for (int jt=0;jt<8;++jt)
    bias[jt] = *reinterpret_cast<const float4*>(bsp + jt*16 + g*4);

  const int l = row0 >> 8, i0 = row0 & 255;
  if (w < 3) {
    f16* ob = (w==0) ? qb : (w==1) ? kbuf : vbuf;
    #pragma unroll
    for (int it=0;it<4;++it) {
      const int i = i0 + it*16 + m;
      #pragma unroll
      for (int jt=0;jt<8;++jt) {
        const int hh = jt >> 1, dh0 = (jt&1)*16 + g*4;
        f16x4 o;
        #pragma unroll
        for (int r=0;r<4;++r) o[r] = (f16)(acc[it][jt][r] + ((const float*)&bias[jt])[r]);
        *reinterpret_cast<f16x4*>(ob + ((size_t)(l*HN + hh)*NDIM + i)*DHD + dh0) = o;
      }
    }
  } else {
    #pragma unroll
    for (int it=0;it<4;++it) {
      const int rowg = row0 + it*16 + m;
      #pragma unroll
      for (int jt=0;jt<8;++jt) {
        f16x4 o;
        #pragma unroll
        for (int r=0;r<4;++r) {
          const float v = acc[it][jt][r] + ((const float*)&bias[jt])[r];
          o[r] = (f16)(1.f/(1.f + __expf(-v)));
        }
        *reinterpret_cast<f16x4*>(gateb + (size_t)rowg*DCC + jt*16 + g*4) = o;
      }
    }
  }
}

// ---------------- K2_BIG: R8 control (fully unrolled, f16 cf) ----------------
__global__ __launch_bounds__(256, 2) void k2_big(
    const f16* __restrict__ qb, const f16* __restrict__ kbuf,
    const f16* __restrict__ vbuf, const float* __restrict__ dist,
    f16* __restrict__ zcom)
{
  __shared__ f16 vt[4*32*256];
  __shared__ f16 cfl[128*64];
  const int t = threadIdx.x;
  const int w = t >> 6, lane = t & 63;
  const int m = lane & 15, g = lane >> 4;
  const int orig = blockIdx.x;
  const int swz = (orig & 7)*64 + (orig >> 3);
  const int l = swz >> 1, half = swz & 1;
  const int r0 = half*128;
  const size_t lb4 = (size_t)l*HN;

  {
    #pragma unroll
    for (int hh = 0; hh < 4; ++hh) {
      const f16x8* vg = reinterpret_cast<const f16x8*>(
          vbuf + (lb4 + hh)*(NDIM*DHD) + (size_t)t*DHD);
      #pragma unroll
      for (int p = 0; p < 4; ++p) {
        f16x8 v = vg[p];
        #pragma unroll
        for (int e = 0; e < 8; ++e) {
          const int c = p*8 + e;
          vt[hh*8192 + c*256 + (((t>>2) ^ (c&15))*4) + (t&3)] = v[e];
        }
      }
    }
  }

  const size_t hb = (lb4 + w) * (NDIM*DHD);
  f16x8 aq[8];
  #pragma unroll
  for (int it = 0; it < 8; ++it)
    aq[it] = *reinterpret_cast<const f16x8*>(qb + hb + (size_t)(r0 + it*16 + m)*DHD + g*8);

  f32x4 o[8][2];
  float rs[8];
  #pragma unroll
  for (int it = 0; it < 8; ++it) {
    o[it][0] = (f32x4){0.f,0.f,0.f,0.f};
    o[it][1] = (f32x4){0.f,0.f,0.f,0.f};
    rs[it] = 0.f;
  }

  const float* drow = dist + (size_t)l*(NDIM*NDIM);
  const f16* vth = vt + w*8192;

  for (int jc = 0; jc < 4; ++jc) {
    __syncthreads();
    #pragma unroll
    for (int p = 0; p < 8; ++p) {
      const int fi = p*256 + t;
      const int row = fi >> 4, f4 = fi & 15;
      const float4 d4 = *reinterpret_cast<const float4*>(
          drow + (size_t)(r0 + row)*NDIM + jc*64 + f4*4);
      f16x4 cf;
      cf[0] = (f16)(CPRE * exp2f(d4.x*d4.x*CEXP));
      cf[1] = (f16)(CPRE * exp2f(d4.y*d4.y*CEXP));
      cf[2] = (f16)(CPRE * exp2f(d4.z*d4.z*CEXP));
      cf[3] = (f16)(CPRE * exp2f(d4.w*d4.w*CEXP));
      *reinterpret_cast<f16x4*>(cfl + row*64 + ((f4 ^ (row & 15))*4)) = cf;
    }
    __syncthreads();

    f16x8 kf[4];
    #pragma unroll
    for (int jt = 0; jt < 4; ++jt)
      kf[jt] = *reinterpret_cast<const f16x8*>(
          kbuf + hb + (size_t)(jc*64 + jt*16 + m)*DHD + g*8);

    f16x8 bvv[2][2];
    #pragma unroll
    for (int kc = 0; kc < 2; ++kc)
      #pragma unroll
      for (int ct = 0; ct < 2; ++ct) {
        const int c = ct*16 + m;
        const f16x4 lo = *reinterpret_cast<const f16x4*>(
            vth + c*256 + (((jc*16 + (2*kc+0)*4 + g) ^ m) * 4));
        const f16x4 hi = *reinterpret_cast<const f16x4*>(
            vth + c*256 + (((jc*16 + (2*kc+1)*4 + g) ^ m) * 4));
        f16x8 bb;
        #pragma unroll
        for (int e = 0; e < 4; ++e) { bb[e] = lo[e]; bb[4+e] = hi[e]; }
        bvv[kc][ct] = bb;
      }

    #pragma unroll
    for (int it = 0; it < 8; ++it) {
      f32x4 s[4];
      #pragma unroll
      for (int jt = 0; jt < 4; ++jt)
        s[jt] = __builtin_amdgcn_mfma_f32_16x16x32_f16(
            kf[jt], aq[it], (f32x4){0.f,0.f,0.f,0.f}, 0, 0, 0);

      const int row = it*16 + m;
      f16x4 pk[4];
      #pragma unroll
      for (int jt = 0; jt < 4; ++jt) {
        const f16x4 cl = *reinterpret_cast<const f16x4*>(
            cfl + row*64 + (((jt*4 + g) ^ (row & 15))*4));
        float psum = 0.f;
        #pragma unroll
        for (int r = 0; r < 4; ++r) {
          const float p = exp2f(s[jt][r] * (float)cl[r]);
          psum += p;
          pk[jt][r] = (f16)p;
        }
        rs[it] += psum;
      }

      #pragma unroll
      for (int kc = 0; kc < 2; ++kc) {
        f16x8 ap;
        #pragma unroll
        for (int e = 0; e < 4; ++e) { ap[e] = pk[2*kc][e]; ap[4+e] = pk[2*kc+1][e]; }
        o[it][0] = __builtin_amdgcn_mfma_f32_16x16x32_f16(ap, bvv[kc][0], o[it][0], 0, 0, 0);
        o[it][1] = __builtin_amdgcn_mfma_f32_16x16x32_f16(ap, bvv[kc][1], o[it][1], 0, 0, 0);
      }
    }
  }

  float rinv[8];
  #pragma unroll
  for (int it = 0; it < 8; ++it) {
    float v = rs[it];
    v += __shfl_xor(v, 16);
    v += __shfl_xor(v, 32);
    rinv[it] = 1.f / v;
  }

  #pragma unroll
  for (int it = 0; it < 8; ++it)
    #pragma unroll
    for (int r = 0; r < 4; ++r) {
      const float rr = __shfl(rinv[it], (lane & 48) + g*4 + r);
      const int row = l*NDIM + r0 + it*16 + g*4 + r;
      #pragma unroll
      for (int ct = 0; ct < 2; ++ct) {
        const int col = w*DHD + ct*16 + m;
        zcom[(size_t)row*DCC + col] = (f16)(o[it][ct][r] * rr);
      }
    }
}

// ---------------- K2_NEW: rolled jc (small code) + f32 cf + pkrtz packing ----------------
__global__ __launch_bounds__(256, 2) void k2_attn(
    const f16* __restrict__ qb, const f16* __restrict__ kbuf,
    const f16* __restrict__ vbuf, const float* __restrict__ dist,
    f16* __restrict__ zcom)
{
  __shared__ f16 vt[4*32*256];   // 64 KB
  __shared__ float cfl[64*64];   // 16 KB f32 coef tile (64 rows)
  const int t = threadIdx.x;
  const int w = t >> 6, lane = t & 63;
  const int m = lane & 15, g = lane >> 4;
  const int orig = blockIdx.x;
  const int swz = (orig & 7)*64 + (orig >> 3);
  const int l = swz >> 1, half = swz & 1;
  const int r0 = half*128;
  const size_t lb4 = (size_t)l*HN;

  {
    #pragma unroll
    for (int hh = 0; hh < 4; ++hh) {
      const f16x8* vg = reinterpret_cast<const f16x8*>(
          vbuf + (lb4 + hh)*(NDIM*DHD) + (size_t)t*DHD);
      #pragma unroll
      for (int p = 0; p < 4; ++p) {
        f16x8 v = vg[p];
        #pragma unroll
        for (int e = 0; e < 8; ++e) {
          const int c = p*8 + e;
          vt[hh*8192 + c*256 + (((t>>2) ^ (c&15))*4) + (t&3)] = v[e];
        }
      }
    }
  }

  const size_t hb = (lb4 + w) * (NDIM*DHD);
  f16x8 aq[8];
  #pragma unroll
  for (int it = 0; it < 8; ++it)
    aq[it] = *reinterpret_cast<const f16x8*>(qb + hb + (size_t)(r0 + it*16 + m)*DHD + g*8);

  f32x4 o[8][2];
  float rs[8];
  #pragma unroll
  for (int it = 0; it < 8; ++it) {
    o[it][0] = (f32x4){0.f,0.f,0.f,0.f};
    o[it][1] = (f32x4){0.f,0.f,0.f,0.f};
    rs[it] = 0.f;
  }

  const float* drow = dist + (size_t)l*(NDIM*NDIM);
  const f16* vth = vt + w*8192;

  #pragma unroll 1
  for (int jc = 0; jc < 4; ++jc) {
    f16x8 kf[4];
    #pragma unroll
    for (int jt = 0; jt < 4; ++jt)
      kf[jt] = *reinterpret_cast<const f16x8*>(
          kbuf + hb + (size_t)(jc*64 + jt*16 + m)*DHD + g*8);

    f16x8 bvv[2][2];
    #pragma unroll
    for (int kc = 0; kc < 2; ++kc)
      #pragma unroll
      for (int ct = 0; ct < 2; ++ct) {
        const int c = ct*16 + m;
        const f16x4 lo = *reinterpret_cast<const f16x4*>(
            vth + c*256 + (((jc*16 + (2*kc+0)*4 + g) ^ m) * 4));
        const f16x4 hi = *reinterpret_cast<const f16x4*>(
            vth + c*256 + (((jc*16 + (2*kc+1)*4 + g) ^ m) * 4));
        f16x8 bb;
        #pragma unroll
        for (int e = 0; e < 4; ++e) { bb[e] = lo[e]; bb[4+e] = hi[e]; }
        bvv[kc][ct] = bb;
      }

    #pragma unroll
    for (int rh = 0; rh < 2; ++rh) {
      __syncthreads();   // prior cfl reads complete
      #pragma unroll
      for (int p = 0; p < 4; ++p) {
        const int fi = p*256 + t;
        const int row = fi >> 4, f4 = fi & 15;
        const float4 d4 = *reinterpret_cast<const float4*>(
            drow + (size_t)(r0 + rh*64 + row)*NDIM + jc*64 + f4*4);
        float4 cf4;
        cf4.x = CPRE * exp2f(d4.x*d4.x*CEXP);
        cf4.y = CPRE * exp2f(d4.y*d4.y*CEXP);
        cf4.z = CPRE * exp2f(d4.z*d4.z*CEXP);
        cf4.w = CPRE * exp2f(d4.w*d4.w*CEXP);
        *reinterpret_cast<float4*>(cfl + row*64 + ((f4 ^ (row & 15))*4)) = cf4;
      }
      __syncthreads();

      #pragma unroll
      for (int itl = 0; itl < 4; ++itl) {
        const int it = rh*4 + itl;
        const int lr = itl*16 + m;
        float4 cl[4];
        #pragma unroll
        for (int jt = 0; jt < 4; ++jt)
          cl[jt] = *reinterpret_cast<const float4*>(
              cfl + lr*64 + (((jt*4 + g) ^ m)*4));

        f32x4 s[4];
        #pragma unroll
        for (int jt = 0; jt < 4; ++jt)
          s[jt] = __builtin_amdgcn_mfma_f32_16x16x32_f16(
              kf[jt], aq[it], (f32x4){0.f,0.f,0.f,0.f}, 0, 0, 0);

        f16x2 pk[4][2];
        #pragma unroll
        for (int jt = 0; jt < 4; ++jt) {
          const float p0 = exp2f(s[jt][0] * cl[jt].x);
          const float p1 = exp2f(s[jt][1] * cl[jt].y);
          const float p2 = exp2f(s[jt][2] * cl[jt].z);
          const float p3 = exp2f(s[jt][3] * cl[jt].w);
          rs[it] += (p0 + p1) + (p2 + p3);
          pk[jt][0] = pkrtz(p0, p1);
          pk[jt][1] = pkrtz(p2, p3);
        }

        #pragma unroll
        for (int kc = 0; kc < 2; ++kc) {
          const f16x4 x = __builtin_shufflevector(pk[2*kc  ][0], pk[2*kc  ][1], 0,1,2,3);
          const f16x4 y = __builtin_shufflevector(pk[2*kc+1][0], pk[2*kc+1][1], 0,1,2,3);
          const f16x8 ap = __builtin_shufflevector(x, y, 0,1,2,3,4,5,6,7);
          o[it][0] = __builtin_amdgcn_mfma_f32_16x16x32_f16(ap, bvv[kc][0], o[it][0], 0, 0, 0);
          o[it][1] = __builtin_amdgcn_mfma_f32_16x16x32_f16(ap, bvv[kc][1], o[it][1], 0, 0, 0);
        }
      }
    }
  }

  float rinv[8];
  #pragma unroll
  for (int it = 0; it < 8; ++it) {
    float v = rs[it];
    v += __shfl_xor(v, 16);
    v += __shfl_xor(v, 32);
    rinv[it] = 1.f / v;
  }

  #pragma unroll
  for (int it = 0; it < 8; ++it)
    #pragma unroll
    for (int r = 0; r < 4; ++r) {
      const float rr = __shfl(rinv[it], (lane & 48) + g*4 + r);
      const int row = l*NDIM + r0 + it*16 + g*4 + r;
      #pragma unroll
      for (int ct = 0; ct < 2; ++ct) {
        const int col = w*DHD + ct*16 + m;
        zcom[(size_t)row*DCC + col] = (f16)(o[it][ct][r] * rr);
      }
    }
}

// ---------------- K3: gated output projection via MFMA ----------------
__global__ __launch_bounds__(256, 4) void k3_out(
    const f16* __restrict__ zcom, const f16* __restrict__ gateb,
    const f16* __restrict__ wo16, const float* __restrict__ bo,
    float* __restrict__ out)
{
  const int t = threadIdx.x;
  const int w = t >> 6, lane = t & 63;
  const int m = lane & 15, g = lane >> 4;
  const size_t row = blockIdx.x*64 + w*16 + m;

  f32x4 acc[8];
  #pragma unroll
  for (int jt=0;jt<8;++jt) acc[jt] = (f32x4){0.f,0.f,0.f,0.f};

  #pragma unroll
  for (int ks = 0; ks < 4; ++ks) {
    f16x8 af[8];
    #pragma unroll
    for (int jt=0;jt<8;++jt)
      af[jt] = *reinterpret_cast<const f16x8*>(wo16 + (jt*16+m)*128 + ks*32 + g*8);
    f16x8 bf = *reinterpret_cast<const f16x8*>(zcom  + row*DCC + ks*32 + g*8);
    f16x8 gf = *reinterpret_cast<const f16x8*>(gateb + row*DCC + ks*32 + g*8);
    bf = bf * gf;
    #pragma unroll
    for (int jt=0;jt<8;++jt)
      acc[jt] = __builtin_amdgcn_mfma_f32_16x16x32_f16(af[jt], bf, acc[jt], 0,0,0);
  }

  #pragma unroll
  for (int jt=0;jt<8;++jt) {
    const float4 bias = *reinterpret_cast<const float4*>(bo + jt*16 + g*4);
    float4 o;
    o.x = acc[jt][0] + bias.x;
    o.y = acc[jt][1] + bias.y;
    o.z = acc[jt][2] + bias.z;
    o.w = acc[jt][3] + bias.w;
    *reinterpret_cast<float4*>(out + row*DZC + jt*16 + g*4) = o;
  }
}

extern "C" void kernel_launch(void* const* d_in, const int* in_sizes, int n_in,
                              void* d_out, int out_size, void* d_ws, size_t ws_size,
                              hipStream_t stream) {
  const float* z    = (const float*)d_in[0];
  const float* dist = (const float*)d_in[1];
  const float* lng  = (const float*)d_in[2];
  const float* lnb  = (const float*)d_in[3];
  const float* Wq   = (const float*)d_in[4];
  const float* bq   = (const float*)d_in[5];
  const float* Wk   = (const float*)d_in[6];
  const float* bk   = (const float*)d_in[7];
  const float* Wv   = (const float*)d_in[8];
  const float* bv   = (const float*)d_in[9];
  const float* Wg   = (const float*)d_in[10];
  const float* bg   = (const float*)d_in[11];
  const float* Wo   = (const float*)d_in[12];
  const float* bo   = (const float*)d_in[13];
  float* out = (float*)d_out;

  const size_t elems = (size_t)MROWS * DCC;  // 8,388,608
  f16* qb    = (f16*)d_ws;
  f16* kbuf  = qb    + elems;
  f16* vbuf  = kbuf  + elems;
  f16* gateb = vbuf  + elems;
  f16* zcom  = gateb + elems;
  f16* w16   = zcom  + elems;   // 5*16384 halves; total ws ≈ 84 MB

  k0b_pack<<<320, 256, 0, stream>>>(Wq, Wk, Wv, Wg, Wo, w16);
  k1_ln_qkvg<<<MROWS/64, 256, 0, stream>>>(z, lng, lnb, w16, bq, bk, bv, bg,
                                           qb, kbuf, vbuf, gateb);
  // A/B probe: control first, candidate LAST (its output is validated)
  k2_big<<<LDIM*2, 256, 0, stream>>>(qb, kbuf, vbuf, dist, zcom);
  k2_attn<<<LDIM*2, 256, 0, stream>>>(qb, kbuf, vbuf, dist, zcom);
  k3_out<<<MROWS/64, 256, 0, stream>>>(zcom, gateb, w16 + 4*16384, bo, out);
}

// Round 12
// 136.736 us; speedup vs baseline: 1.2005x; 1.2005x over previous
//
#include <hip/hip_runtime.h>
#include <hip/hip_fp16.h>

#define LDIM 256
#define NDIM 256
#define DZC  128
#define HN   4
#define DHD  32
#define DCC  128
#define MROWS (LDIM*NDIM)

typedef _Float16 f16;
typedef _Float16 f16x2 __attribute__((ext_vector_type(2)));
typedef _Float16 f16x4 __attribute__((ext_vector_type(4)));
typedef _Float16 f16x8 __attribute__((ext_vector_type(8)));
typedef __fp16   h16x2 __attribute__((ext_vector_type(2)));
typedef float    f32x4 __attribute__((ext_vector_type(4)));

#define SCAL 0.17677669529663687f      // 1/sqrt(32)
#define CEXP -0.011270992135622957f    // -log2(e)/128
#define CPRE 0.2550340490960039f       // SCAL * log2(e)

__device__ inline f16x2 pkrtz(float a, float b){
  h16x2 r = __builtin_amdgcn_cvt_pkrtz(a, b);
  union { h16x2 h; f16x2 f; } u; u.h = r;
  return u.f;
}

// ---------------- K0b: pack W^T f16 — w16[p][col][k] = W_p[k][col] ----------------
__global__ __launch_bounds__(256) void k0b_pack(
    const float* __restrict__ Wq, const float* __restrict__ Wk,
    const float* __restrict__ Wv, const float* __restrict__ Wg,
    const float* __restrict__ Wo, f16* __restrict__ w16)
{
  const float* Ws[5] = {Wq, Wk, Wv, Wg, Wo};
  const int tid = blockIdx.x * 256 + threadIdx.x;
  const int p = tid >> 14, rem = tid & 16383;
  const int col = rem >> 7, k = rem & 127;
  w16[tid] = (f16)Ws[p][k*128 + col];
}

// ---------------- K1: LN + Q/K/V/Gate via MFMA ----------------
__global__ __launch_bounds__(256, 2) void k1_ln_qkvg(
    const float* __restrict__ z, const float* __restrict__ lng, const float* __restrict__ lnb,
    const f16* __restrict__ w16,
    const float* __restrict__ bq, const float* __restrict__ bk,
    const float* __restrict__ bv, const float* __restrict__ bg,
    f16* __restrict__ qb, f16* __restrict__ kbuf,
    f16* __restrict__ vbuf, f16* __restrict__ gateb)
{
  __shared__ f16 zl[64*128];   // 16 KB
  const int t = threadIdx.x;
  const int w = t >> 6, lane = t & 63;
  const int m = lane & 15, g = lane >> 4;
  const int row0 = blockIdx.x * 64;

  {
    const int r = t >> 2, part = t & 3;
    const float* zr = z + (size_t)(row0 + r)*DZC + part*32;
    float vals[32];
    float s = 0.f, sq = 0.f;
    #pragma unroll
    for (int i = 0; i < 8; ++i) {
      float4 v4 = reinterpret_cast<const float4*>(zr)[i];
      vals[i*4+0]=v4.x; vals[i*4+1]=v4.y; vals[i*4+2]=v4.z; vals[i*4+3]=v4.w;
      s  += v4.x+v4.y+v4.z+v4.w;
      sq += v4.x*v4.x + v4.y*v4.y + v4.z*v4.z + v4.w*v4.w;
    }
    s  += __shfl_xor(s, 1);  sq += __shfl_xor(sq, 1);
    s  += __shfl_xor(s, 2);  sq += __shfl_xor(sq, 2);
    const float mu  = s * (1.f/DZC);
    const float var = sq * (1.f/DZC) - mu*mu;
    const float rstd = rsqrtf(var + 1e-5f);
    const float* gg = lng + part*32;
    const float* bb = lnb + part*32;
    #pragma unroll
    for (int i = 0; i < 4; ++i) {
      f16x8 o;
      #pragma unroll
      for (int e = 0; e < 8; ++e)
        o[e] = (f16)((vals[i*8+e]-mu)*rstd*gg[i*8+e] + bb[i*8+e]);
      *reinterpret_cast<f16x8*>(zl + r*128 + (((part*4+i) ^ (r&7))*8)) = o;
    }
  }
  __syncthreads();

  const f16* wp = w16 + w*16384;
  f32x4 acc[4][8];
  #pragma unroll
  for (int it=0;it<4;++it)
    #pragma unroll
    for (int jt=0;jt<8;++jt) acc[it][jt] = (f32x4){0.f,0.f,0.f,0.f};

  #pragma unroll
  for (int ks = 0; ks < 4; ++ks) {
    f16x8 af[8];
    #pragma unroll
    for (int jt=0;jt<8;++jt)
      af[jt] = *reinterpret_cast<const f16x8*>(wp + (jt*16+m)*128 + ks*32 + g*8);
    f16x8 bf[4];
    #pragma unroll
    for (int it=0;it<4;++it)
      bf[it] = *reinterpret_cast<const f16x8*>(zl + (it*16+m)*128 + (((ks*4+g) ^ (m&7))*8));
    #pragma unroll
    for (int it=0;it<4;++it)
      #pragma unroll
      for (int jt=0;jt<8;++jt)
        acc[it][jt] = __builtin_amdgcn_mfma_f32_16x16x32_f16(af[jt], bf[it], acc[it][jt], 0,0,0);
  }

  const float* bsp = (w==0) ? bq : (w==1) ? bk : (w==2) ? bv : bg;
  float4 bias[8];
  #pragma unroll
  for (int jt=0;jt<8;++jt)
    bias[jt] = *reinterpret_cast<const float4*>(bsp + jt*16 + g*4);

  const int l = row0 >> 8, i0 = row0 & 255;
  if (w < 3) {
    f16* ob = (w==0) ? qb : (w==1) ? kbuf : vbuf;
    #pragma unroll
    for (int it=0;it<4;++it) {
      const int i = i0 + it*16 + m;
      #pragma unroll
      for (int jt=0;jt<8;++jt) {
        const int hh = jt >> 1, dh0 = (jt&1)*16 + g*4;
        f16x4 o;
        #pragma unroll
        for (int r=0;r<4;++r) o[r] = (f16)(acc[it][jt][r] + ((const float*)&bias[jt])[r]);
        *reinterpret_cast<f16x4*>(ob + ((size_t)(l*HN + hh)*NDIM + i)*DHD + dh0) = o;
      }
    }
  } else {
    #pragma unroll
    for (int it=0;it<4;++it) {
      const int rowg = row0 + it*16 + m;
      #pragma unroll
      for (int jt=0;jt<8;++jt) {
        f16x4 o;
        #pragma unroll
        for (int r=0;r<4;++r) {
          const float v = acc[it][jt][r] + ((const float*)&bias[jt])[r];
          o[r] = (f16)(1.f/(1.f + __expf(-v)));
        }
        *reinterpret_cast<f16x4*>(gateb + (size_t)rowg*DCC + jt*16 + g*4) = o;
      }
    }
  }
}

// ---------------- K2: block = (l, half128, hpair); wave = (head, row64) ----------------
// Rolled jc + VALU diet (R10 winner) + 1.5x occupancy: LDS = VT 2 heads (32KB)
// + cf f16 128x64 (16KB) = 48KB -> 3 blocks/CU, 12 waves/CU. Per-thread logits
// halved (256). cf staged once per jc for all 128 rows (one sync pair).
__global__ __launch_bounds__(256, 3) void k2_attn(
    const f16* __restrict__ qb, const f16* __restrict__ kbuf,
    const f16* __restrict__ vbuf, const float* __restrict__ dist,
    f16* __restrict__ zcom)
{
  __shared__ f16 vt[2*32*256];   // 32 KB, 2 heads swizzled V^T
  __shared__ f16 cfl[128*64];    // 16 KB f16 coef tile
  const int t = threadIdx.x;
  const int w = t >> 6, lane = t & 63;
  const int m = lane & 15, g = lane >> 4;
  const int orig = blockIdx.x;
  const int swz = (orig & 7)*128 + (orig >> 3);   // bijective XCD swizzle (1024%8==0)
  const int l = swz >> 2, half = (swz >> 1) & 1, hp = swz & 1;
  const int r0b = half*128;                       // block's first query row
  const size_t lb4 = (size_t)l*HN;
  const int hl = w >> 1;                          // wave's head within pair
  const int rw = (w & 1)*64;                      // wave's row offset in block

  { // build VT for the 2 heads of this pair
    #pragma unroll
    for (int hh = 0; hh < 2; ++hh) {
      const f16x8* vg = reinterpret_cast<const f16x8*>(
          vbuf + (lb4 + hp*2 + hh)*(NDIM*DHD) + (size_t)t*DHD);
      #pragma unroll
      for (int p = 0; p < 4; ++p) {
        f16x8 v = vg[p];
        #pragma unroll
        for (int e = 0; e < 8; ++e) {
          const int c = p*8 + e;
          vt[hh*8192 + c*256 + (((t>>2) ^ (c&15))*4) + (t&3)] = v[e];
        }
      }
    }
  }

  const size_t hb = (lb4 + hp*2 + hl) * (NDIM*DHD);
  f16x8 aq[4];
  #pragma unroll
  for (int it = 0; it < 4; ++it)
    aq[it] = *reinterpret_cast<const f16x8*>(
        qb + hb + (size_t)(r0b + rw + it*16 + m)*DHD + g*8);

  f32x4 o[4][2];
  float rs[4];
  #pragma unroll
  for (int it = 0; it < 4; ++it) {
    o[it][0] = (f32x4){0.f,0.f,0.f,0.f};
    o[it][1] = (f32x4){0.f,0.f,0.f,0.f};
    rs[it] = 0.f;
  }

  const float* drow = dist + (size_t)l*(NDIM*NDIM);
  const f16* vth = vt + hl*8192;

  #pragma unroll 1
  for (int jc = 0; jc < 4; ++jc) {
    __syncthreads();   // prior-jc cfl reads done (covers VT build on jc=0)
    // ---- stage cf tile: 128 rows x 64 j, f16, coalesced dist reads ----
    #pragma unroll
    for (int p = 0; p < 8; ++p) {
      const int fi = p*256 + t;              // 2048 float4 granules
      const int row = fi >> 4, f4 = fi & 15;
      const float4 d4 = *reinterpret_cast<const float4*>(
          drow + (size_t)(r0b + row)*NDIM + jc*64 + f4*4);
      const f16x2 a = pkrtz(CPRE*exp2f(d4.x*d4.x*CEXP), CPRE*exp2f(d4.y*d4.y*CEXP));
      const f16x2 b = pkrtz(CPRE*exp2f(d4.z*d4.z*CEXP), CPRE*exp2f(d4.w*d4.w*CEXP));
      const f16x4 cf = __builtin_shufflevector(a, b, 0,1,2,3);
      *reinterpret_cast<f16x4*>(cfl + row*64 + ((f4 ^ (row & 15))*4)) = cf;
    }
    __syncthreads();

    f16x8 kf[4];
    #pragma unroll
    for (int jt = 0; jt < 4; ++jt)
      kf[jt] = *reinterpret_cast<const f16x8*>(
          kbuf + hb + (size_t)(jc*64 + jt*16 + m)*DHD + g*8);

    f16x8 bvv[2][2];
    #pragma unroll
    for (int kc = 0; kc < 2; ++kc)
      #pragma unroll
      for (int ct = 0; ct < 2; ++ct) {
        const int c = ct*16 + m;
        const f16x4 lo = *reinterpret_cast<const f16x4*>(
            vth + c*256 + (((jc*16 + (2*kc+0)*4 + g) ^ m) * 4));
        const f16x4 hi = *reinterpret_cast<const f16x4*>(
            vth + c*256 + (((jc*16 + (2*kc+1)*4 + g) ^ m) * 4));
        f16x8 bb;
        #pragma unroll
        for (int e = 0; e < 4; ++e) { bb[e] = lo[e]; bb[4+e] = hi[e]; }
        bvv[kc][ct] = bb;
      }

    #pragma unroll
    for (int it = 0; it < 4; ++it) {
      const int lr = rw + it*16 + m;         // row within 128-row cf tile
      f16x4 cl[4];
      #pragma unroll
      for (int jt = 0; jt < 4; ++jt)
        cl[jt] = *reinterpret_cast<const f16x4*>(
            cfl + lr*64 + (((jt*4 + g) ^ (lr & 15))*4));

      f32x4 s[4];
      #pragma unroll
      for (int jt = 0; jt < 4; ++jt)
        s[jt] = __builtin_amdgcn_mfma_f32_16x16x32_f16(
            kf[jt], aq[it], (f32x4){0.f,0.f,0.f,0.f}, 0, 0, 0);

      f16x2 pk[4][2];
      #pragma unroll
      for (int jt = 0; jt < 4; ++jt) {
        const float p0 = exp2f(s[jt][0] * (float)cl[jt][0]);
        const float p1 = exp2f(s[jt][1] * (float)cl[jt][1]);
        const float p2 = exp2f(s[jt][2] * (float)cl[jt][2]);
        const float p3 = exp2f(s[jt][3] * (float)cl[jt][3]);
        rs[it] += (p0 + p1) + (p2 + p3);
        pk[jt][0] = pkrtz(p0, p1);
        pk[jt][1] = pkrtz(p2, p3);
      }

      #pragma unroll
      for (int kc = 0; kc < 2; ++kc) {
        const f16x4 x = __builtin_shufflevector(pk[2*kc  ][0], pk[2*kc  ][1], 0,1,2,3);
        const f16x4 y = __builtin_shufflevector(pk[2*kc+1][0], pk[2*kc+1][1], 0,1,2,3);
        const f16x8 ap = __builtin_shufflevector(x, y, 0,1,2,3,4,5,6,7);
        o[it][0] = __builtin_amdgcn_mfma_f32_16x16x32_f16(ap, bvv[kc][0], o[it][0], 0, 0, 0);
        o[it][1] = __builtin_amdgcn_mfma_f32_16x16x32_f16(ap, bvv[kc][1], o[it][1], 0, 0, 0);
      }
    }
  }

  float rinv[4];
  #pragma unroll
  for (int it = 0; it < 4; ++it) {
    float v = rs[it];
    v += __shfl_xor(v, 16);
    v += __shfl_xor(v, 32);
    rinv[it] = 1.f / v;
  }

  // epilogue: normalize + store (gate applied in k3)
  const int h = hp*2 + hl;
  #pragma unroll
  for (int it = 0; it < 4; ++it)
    #pragma unroll
    for (int r = 0; r < 4; ++r) {
      const float rr = __shfl(rinv[it], (lane & 48) + g*4 + r);
      const int row = l*NDIM + r0b + rw + it*16 + g*4 + r;
      #pragma unroll
      for (int ct = 0; ct < 2; ++ct) {
        const int col = h*DHD + ct*16 + m;
        zcom[(size_t)row*DCC + col] = (f16)(o[it][ct][r] * rr);
      }
    }
}

// ---------------- K3: gated output projection via MFMA ----------------
__global__ __launch_bounds__(256, 4) void k3_out(
    const f16* __restrict__ zcom, const f16* __restrict__ gateb,
    const f16* __restrict__ wo16, const float* __restrict__ bo,
    float* __restrict__ out)
{
  const int t = threadIdx.x;
  const int w = t >> 6, lane = t & 63;
  const int m = lane & 15, g = lane >> 4;
  const size_t row = blockIdx.x*64 + w*16 + m;

  f32x4 acc[8];
  #pragma unroll
  for (int jt=0;jt<8;++jt) acc[jt] = (f32x4){0.f,0.f,0.f,0.f};

  #pragma unroll
  for (int ks = 0; ks < 4; ++ks) {
    f16x8 af[8];
    #pragma unroll
    for (int jt=0;jt<8;++jt)
      af[jt] = *reinterpret_cast<const f16x8*>(wo16 + (jt*16+m)*128 + ks*32 + g*8);
    f16x8 bf = *reinterpret_cast<const f16x8*>(zcom  + row*DCC + ks*32 + g*8);
    f16x8 gf = *reinterpret_cast<const f16x8*>(gateb + row*DCC + ks*32 + g*8);
    bf = bf * gf;
    #pragma unroll
    for (int jt=0;jt<8;++jt)
      acc[jt] = __builtin_amdgcn_mfma_f32_16x16x32_f16(af[jt], bf, acc[jt], 0,0,0);
  }

  #pragma unroll
  for (int jt=0;jt<8;++jt) {
    const float4 bias = *reinterpret_cast<const float4*>(bo + jt*16 + g*4);
    float4 o;
    o.x = acc[jt][0] + bias.x;
    o.y = acc[jt][1] + bias.y;
    o.z = acc[jt][2] + bias.z;
    o.w = acc[jt][3] + bias.w;
    *reinterpret_cast<float4*>(out + row*DZC + jt*16 + g*4) = o;
  }
}

extern "C" void kernel_launch(void* const* d_in, const int* in_sizes, int n_in,
                              void* d_out, int out_size, void* d_ws, size_t ws_size,
                              hipStream_t stream) {
  const float* z    = (const float*)d_in[0];
  const float* dist = (const float*)d_in[1];
  const float* lng  = (const float*)d_in[2];
  const float* lnb  = (const float*)d_in[3];
  const float* Wq   = (const float*)d_in[4];
  const float* bq   = (const float*)d_in[5];
  const float* Wk   = (const float*)d_in[6];
  const float* bk   = (const float*)d_in[7];
  const float* Wv   = (const float*)d_in[8];
  const float* bv   = (const float*)d_in[9];
  const float* Wg   = (const float*)d_in[10];
  const float* bg   = (const float*)d_in[11];
  const float* Wo   = (const float*)d_in[12];
  const float* bo   = (const float*)d_in[13];
  float* out = (float*)d_out;

  const size_t elems = (size_t)MROWS * DCC;  // 8,388,608
  f16* qb    = (f16*)d_ws;
  f16* kbuf  = qb    + elems;
  f16* vbuf  = kbuf  + elems;
  f16* gateb = vbuf  + elems;
  f16* zcom  = gateb + elems;
  f16* w16   = zcom  + elems;   // 5*16384 halves; total ws ≈ 84 MB

  k0b_pack<<<320, 256, 0, stream>>>(Wq, Wk, Wv, Wg, Wo, w16);
  k1_ln_qkvg<<<MROWS/64, 256, 0, stream>>>(z, lng, lnb, w16, bq, bk, bv, bg,
                                           qb, kbuf, vbuf, gateb);
  k2_attn<<<LDIM*4, 256, 0, stream>>>(qb, kbuf, vbuf, dist, zcom);
  k3_out<<<MROWS/64, 256, 0, stream>>>(zcom, gateb, w16 + 4*16384, bo, out);
}

// Round 14
// 118.833 us; speedup vs baseline: 1.3813x; 1.1507x over previous
//
#include <hip/hip_runtime.h>
#include <hip/hip_fp16.h>

#define LDIM 256
#define NDIM 256
#define DZC  128
#define HN   4
#define DHD  32
#define DCC  128
#define MROWS (LDIM*NDIM)

typedef _Float16 f16;
typedef _Float16 f16x2 __attribute__((ext_vector_type(2)));
typedef _Float16 f16x4 __attribute__((ext_vector_type(4)));
typedef _Float16 f16x8 __attribute__((ext_vector_type(8)));
typedef __fp16   h16x2 __attribute__((ext_vector_type(2)));
typedef float    f32x4 __attribute__((ext_vector_type(4)));

#define SCAL 0.17677669529663687f      // 1/sqrt(32)
#define CEXP -0.011270992135622957f    // -log2(e)/128
#define CPRE 0.2550340490960039f       // SCAL * log2(e)

__device__ inline f16x2 pkrtz(float a, float b){
  h16x2 r = __builtin_amdgcn_cvt_pkrtz(a, b);
  union { h16x2 h; f16x2 f; } u; u.h = r;
  return u.f;
}

// ---------------- K0b: pack W^T f16 — w16[p][col][k] = W_p[k][col] ----------------
__global__ __launch_bounds__(256) void k0b_pack(
    const float* __restrict__ Wq, const float* __restrict__ Wk,
    const float* __restrict__ Wv, const float* __restrict__ Wg,
    const float* __restrict__ Wo, f16* __restrict__ w16)
{
  const float* Ws[5] = {Wq, Wk, Wv, Wg, Wo};
  const int tid = blockIdx.x * 256 + threadIdx.x;
  const int p = tid >> 14, rem = tid & 16383;
  const int col = rem >> 7, k = rem & 127;
  w16[tid] = (f16)Ws[p][k*128 + col];
}

// ---------------- K1: LN + Q/K/V/Gate via MFMA ----------------
__global__ __launch_bounds__(256, 2) void k1_ln_qkvg(
    const float* __restrict__ z, const float* __restrict__ lng, const float* __restrict__ lnb,
    const f16* __restrict__ w16,
    const float* __restrict__ bq, const float* __restrict__ bk,
    const float* __restrict__ bv, const float* __restrict__ bg,
    f16* __restrict__ qb, f16* __restrict__ kbuf,
    f16* __restrict__ vbuf, f16* __restrict__ gateb)
{
  __shared__ f16 zl[64*128];   // 16 KB
  const int t = threadIdx.x;
  const int w = t >> 6, lane = t & 63;
  const int m = lane & 15, g = lane >> 4;
  const int row0 = blockIdx.x * 64;

  {
    const int r = t >> 2, part = t & 3;
    const float* zr = z + (size_t)(row0 + r)*DZC + part*32;
    float vals[32];
    float s = 0.f, sq = 0.f;
    #pragma unroll
    for (int i = 0; i < 8; ++i) {
      float4 v4 = reinterpret_cast<const float4*>(zr)[i];
      vals[i*4+0]=v4.x; vals[i*4+1]=v4.y; vals[i*4+2]=v4.z; vals[i*4+3]=v4.w;
      s  += v4.x+v4.y+v4.z+v4.w;
      sq += v4.x*v4.x + v4.y*v4.y + v4.z*v4.z + v4.w*v4.w;
    }
    s  += __shfl_xor(s, 1);  sq += __shfl_xor(sq, 1);
    s  += __shfl_xor(s, 2);  sq += __shfl_xor(sq, 2);
    const float mu  = s * (1.f/DZC);
    const float var = sq * (1.f/DZC) - mu*mu;
    const float rstd = rsqrtf(var + 1e-5f);
    const float* gg = lng + part*32;
    const float* bb = lnb + part*32;
    #pragma unroll
    for (int i = 0; i < 4; ++i) {
      f16x8 o;
      #pragma unroll
      for (int e = 0; e < 8; ++e)
        o[e] = (f16)((vals[i*8+e]-mu)*rstd*gg[i*8+e] + bb[i*8+e]);
      *reinterpret_cast<f16x8*>(zl + r*128 + (((part*4+i) ^ (r&7))*8)) = o;
    }
  }
  __syncthreads();

  const f16* wp = w16 + w*16384;
  f32x4 acc[4][8];
  #pragma unroll
  for (int it=0;it<4;++it)
    #pragma unroll
    for (int jt=0;jt<8;++jt) acc[it][jt] = (f32x4){0.f,0.f,0.f,0.f};

  #pragma unroll
  for (int ks = 0; ks < 4; ++ks) {
    f16x8 af[8];
    #pragma unroll
    for (int jt=0;jt<8;++jt)
      af[jt] = *reinterpret_cast<const f16x8*>(wp + (jt*16+m)*128 + ks*32 + g*8);
    f16x8 bf[4];
    #pragma unroll
    for (int it=0;it<4;++it)
      bf[it] = *reinterpret_cast<const f16x8*>(zl + (it*16+m)*128 + (((ks*4+g) ^ (m&7))*8));
    #pragma unroll
    for (int it=0;it<4;++it)
      #pragma unroll
      for (int jt=0;jt<8;++jt)
        acc[it][jt] = __builtin_amdgcn_mfma_f32_16x16x32_f16(af[jt], bf[it], acc[it][jt], 0,0,0);
  }

  const float* bsp = (w==0) ? bq : (w==1) ? bk : (w==2) ? bv : bg;
  float4 bias[8];
  #pragma unroll
  for (int jt=0;jt<8;++jt)
    bias[jt] = *reinterpret_cast<const float4*>(bsp + jt*16 + g*4);

  const int l = row0 >> 8, i0 = row0 & 255;
  if (w < 3) {
    f16* ob = (w==0) ? qb : (w==1) ? kbuf : vbuf;
    #pragma unroll
    for (int it=0;it<4;++it) {
      const int i = i0 + it*16 + m;
      #pragma unroll
      for (int jt=0;jt<8;++jt) {
        const int hh = jt >> 1, dh0 = (jt&1)*16 + g*4;
        f16x4 o;
        #pragma unroll
        for (int r=0;r<4;++r) o[r] = (f16)(acc[it][jt][r] + ((const float*)&bias[jt])[r]);
        *reinterpret_cast<f16x4*>(ob + ((size_t)(l*HN + hh)*NDIM + i)*DHD + dh0) = o;
      }
    }
  } else {
    #pragma unroll
    for (int it=0;it<4;++it) {
      const int rowg = row0 + it*16 + m;
      #pragma unroll
      for (int jt=0;jt<8;++jt) {
        f16x4 o;
        #pragma unroll
        for (int r=0;r<4;++r) {
          const float v = acc[it][jt][r] + ((const float*)&bias[jt])[r];
          o[r] = (f16)(1.f/(1.f + __expf(-v)));
        }
        *reinterpret_cast<f16x4*>(gateb + (size_t)rowg*DCC + jt*16 + g*4) = o;
      }
    }
  }
}

// ---------------- K2: rolled jc + f32 cf + pkrtz, 512 blocks ----------------
// block = (l, half128), wave = head, 8 its/wave. launch_bounds(256,2): no spill.
// FIX vs R12: __syncthreads() after VT build — bvv loads for jc=0 read vt
// before the first in-loop barrier, racing other waves' VT writes.
__global__ __launch_bounds__(256, 2) void k2_attn(
    const f16* __restrict__ qb, const f16* __restrict__ kbuf,
    const f16* __restrict__ vbuf, const float* __restrict__ dist,
    f16* __restrict__ zcom)
{
  __shared__ f16 vt[4*32*256];   // 64 KB, per-head swizzled V^T
  __shared__ float cfl[64*64];   // 16 KB f32 coef tile (64 rows)
  const int t = threadIdx.x;
  const int w = t >> 6, lane = t & 63;
  const int m = lane & 15, g = lane >> 4;
  const int orig = blockIdx.x;
  const int swz = (orig & 7)*64 + (orig >> 3);   // bijective XCD swizzle (512%8==0)
  const int l = swz >> 1, half = swz & 1;
  const int r0 = half*128;
  const size_t lb4 = (size_t)l*HN;

  {
    #pragma unroll
    for (int hh = 0; hh < 4; ++hh) {
      const f16x8* vg = reinterpret_cast<const f16x8*>(
          vbuf + (lb4 + hh)*(NDIM*DHD) + (size_t)t*DHD);
      #pragma unroll
      for (int p = 0; p < 4; ++p) {
        f16x8 v = vg[p];
        #pragma unroll
        for (int e = 0; e < 8; ++e) {
          const int c = p*8 + e;
          vt[hh*8192 + c*256 + (((t>>2) ^ (c&15))*4) + (t&3)] = v[e];
        }
      }
    }
  }

  const size_t hb = (lb4 + w) * (NDIM*DHD);
  f16x8 aq[8];
  #pragma unroll
  for (int it = 0; it < 8; ++it)
    aq[it] = *reinterpret_cast<const f16x8*>(qb + hb + (size_t)(r0 + it*16 + m)*DHD + g*8);

  f32x4 o[8][2];
  float rs[8];
  #pragma unroll
  for (int it = 0; it < 8; ++it) {
    o[it][0] = (f32x4){0.f,0.f,0.f,0.f};
    o[it][1] = (f32x4){0.f,0.f,0.f,0.f};
    rs[it] = 0.f;
  }

  __syncthreads();   // VT build complete before any wave reads vt (R12 race fix)

  const float* drow = dist + (size_t)l*(NDIM*NDIM);
  const f16* vth = vt + w*8192;

  #pragma unroll 1
  for (int jc = 0; jc < 4; ++jc) {
    f16x8 kf[4];
    #pragma unroll
    for (int jt = 0; jt < 4; ++jt)
      kf[jt] = *reinterpret_cast<const f16x8*>(
          kbuf + hb + (size_t)(jc*64 + jt*16 + m)*DHD + g*8);

    f16x8 bvv[2][2];
    #pragma unroll
    for (int kc = 0; kc < 2; ++kc)
      #pragma unroll
      for (int ct = 0; ct < 2; ++ct) {
        const int c = ct*16 + m;
        const f16x4 lo = *reinterpret_cast<const f16x4*>(
            vth + c*256 + (((jc*16 + (2*kc+0)*4 + g) ^ m) * 4));
        const f16x4 hi = *reinterpret_cast<const f16x4*>(
            vth + c*256 + (((jc*16 + (2*kc+1)*4 + g) ^ m) * 4));
        f16x8 bb;
        #pragma unroll
        for (int e = 0; e < 4; ++e) { bb[e] = lo[e]; bb[4+e] = hi[e]; }
        bvv[kc][ct] = bb;
      }

    #pragma unroll
    for (int rh = 0; rh < 2; ++rh) {
      __syncthreads();   // prior cfl reads complete
      #pragma unroll
      for (int p = 0; p < 4; ++p) {
        const int fi = p*256 + t;
        const int row = fi >> 4, f4 = fi & 15;
        const float4 d4 = *reinterpret_cast<const float4*>(
            drow + (size_t)(r0 + rh*64 + row)*NDIM + jc*64 + f4*4);
        float4 cf4;
        cf4.x = CPRE * exp2f(d4.x*d4.x*CEXP);
        cf4.y = CPRE * exp2f(d4.y*d4.y*CEXP);
        cf4.z = CPRE * exp2f(d4.z*d4.z*CEXP);
        cf4.w = CPRE * exp2f(d4.w*d4.w*CEXP);
        *reinterpret_cast<float4*>(cfl + row*64 + ((f4 ^ (row & 15))*4)) = cf4;
      }
      __syncthreads();

      #pragma unroll
      for (int itl = 0; itl < 4; ++itl) {
        const int it = rh*4 + itl;
        const int lr = itl*16 + m;
        float4 cl[4];
        #pragma unroll
        for (int jt = 0; jt < 4; ++jt)
          cl[jt] = *reinterpret_cast<const float4*>(
              cfl + lr*64 + (((jt*4 + g) ^ m)*4));

        f32x4 s[4];
        #pragma unroll
        for (int jt = 0; jt < 4; ++jt)
          s[jt] = __builtin_amdgcn_mfma_f32_16x16x32_f16(
              kf[jt], aq[it], (f32x4){0.f,0.f,0.f,0.f}, 0, 0, 0);

        f16x2 pk[4][2];
        #pragma unroll
        for (int jt = 0; jt < 4; ++jt) {
          const float p0 = exp2f(s[jt][0] * cl[jt].x);
          const float p1 = exp2f(s[jt][1] * cl[jt].y);
          const float p2 = exp2f(s[jt][2] * cl[jt].z);
          const float p3 = exp2f(s[jt][3] * cl[jt].w);
          rs[it] += (p0 + p1) + (p2 + p3);
          pk[jt][0] = pkrtz(p0, p1);
          pk[jt][1] = pkrtz(p2, p3);
        }

        #pragma unroll
        for (int kc = 0; kc < 2; ++kc) {
          const f16x4 x = __builtin_shufflevector(pk[2*kc  ][0], pk[2*kc  ][1], 0,1,2,3);
          const f16x4 y = __builtin_shufflevector(pk[2*kc+1][0], pk[2*kc+1][1], 0,1,2,3);
          const f16x8 ap = __builtin_shufflevector(x, y, 0,1,2,3,4,5,6,7);
          o[it][0] = __builtin_amdgcn_mfma_f32_16x16x32_f16(ap, bvv[kc][0], o[it][0], 0, 0, 0);
          o[it][1] = __builtin_amdgcn_mfma_f32_16x16x32_f16(ap, bvv[kc][1], o[it][1], 0, 0, 0);
        }
      }
    }
  }

  float rinv[8];
  #pragma unroll
  for (int it = 0; it < 8; ++it) {
    float v = rs[it];
    v += __shfl_xor(v, 16);
    v += __shfl_xor(v, 32);
    rinv[it] = 1.f / v;
  }

  #pragma unroll
  for (int it = 0; it < 8; ++it)
    #pragma unroll
    for (int r = 0; r < 4; ++r) {
      const float rr = __shfl(rinv[it], (lane & 48) + g*4 + r);
      const int row = l*NDIM + r0 + it*16 + g*4 + r;
      #pragma unroll
      for (int ct = 0; ct < 2; ++ct) {
        const int col = w*DHD + ct*16 + m;
        zcom[(size_t)row*DCC + col] = (f16)(o[it][ct][r] * rr);
      }
    }
}

// ---------------- K3: gated output projection via MFMA ----------------
__global__ __launch_bounds__(256, 4) void k3_out(
    const f16* __restrict__ zcom, const f16* __restrict__ gateb,
    const f16* __restrict__ wo16, const float* __restrict__ bo,
    float* __restrict__ out)
{
  const int t = threadIdx.x;
  const int w = t >> 6, lane = t & 63;
  const int m = lane & 15, g = lane >> 4;
  const size_t row = blockIdx.x*64 + w*16 + m;

  f32x4 acc[8];
  #pragma unroll
  for (int jt=0;jt<8;++jt) acc[jt] = (f32x4){0.f,0.f,0.f,0.f};

  #pragma unroll
  for (int ks = 0; ks < 4; ++ks) {
    f16x8 af[8];
    #pragma unroll
    for (int jt=0;jt<8;++jt)
      af[jt] = *reinterpret_cast<const f16x8*>(wo16 + (jt*16+m)*128 + ks*32 + g*8);
    f16x8 bf = *reinterpret_cast<const f16x8*>(zcom  + row*DCC + ks*32 + g*8);
    f16x8 gf = *reinterpret_cast<const f16x8*>(gateb + row*DCC + ks*32 + g*8);
    bf = bf * gf;
    #pragma unroll
    for (int jt=0;jt<8;++jt)
      acc[jt] = __builtin_amdgcn_mfma_f32_16x16x32_f16(af[jt], bf, acc[jt], 0,0,0);
  }

  #pragma unroll
  for (int jt=0;jt<8;++jt) {
    const float4 bias = *reinterpret_cast<const float4*>(bo + jt*16 + g*4);
    float4 o;
    o.x = acc[jt][0] + bias.x;
    o.y = acc[jt][1] + bias.y;
    o.z = acc[jt][2] + bias.z;
    o.w = acc[jt][3] + bias.w;
    *reinterpret_cast<float4*>(out + row*DZC + jt*16 + g*4) = o;
  }
}

extern "C" void kernel_launch(void* const* d_in, const int* in_sizes, int n_in,
                              void* d_out, int out_size, void* d_ws, size_t ws_size,
                              hipStream_t stream) {
  const float* z    = (const float*)d_in[0];
  const float* dist = (const float*)d_in[1];
  const float* lng  = (const float*)d_in[2];
  const float* lnb  = (const float*)d_in[3];
  const float* Wq   = (const float*)d_in[4];
  const float* bq   = (const float*)d_in[5];
  const float* Wk   = (const float*)d_in[6];
  const float* bk   = (const float*)d_in[7];
  const float* Wv   = (const float*)d_in[8];
  const float* bv   = (const float*)d_in[9];
  const float* Wg   = (const float*)d_in[10];
  const float* bg   = (const float*)d_in[11];
  const float* Wo   = (const float*)d_in[12];
  const float* bo   = (const float*)d_in[13];
  float* out = (float*)d_out;

  const size_t elems = (size_t)MROWS * DCC;  // 8,388,608
  f16* qb    = (f16*)d_ws;
  f16* kbuf  = qb    + elems;
  f16* vbuf  = kbuf  + elems;
  f16* gateb = vbuf  + elems;
  f16* zcom  = gateb + elems;
  f16* w16   = zcom  + elems;   // 5*16384 halves; total ws ≈ 84 MB

  k0b_pack<<<320, 256, 0, stream>>>(Wq, Wk, Wv, Wg, Wo, w16);
  k1_ln_qkvg<<<MROWS/64, 256, 0, stream>>>(z, lng, lnb, w16, bq, bk, bv, bg,
                                           qb, kbuf, vbuf, gateb);
  k2_attn<<<LDIM*2, 256, 0, stream>>>(qb, kbuf, vbuf, dist, zcom);
  k3_out<<<MROWS/64, 256, 0, stream>>>(zcom, gateb, w16 + 4*16384, bo, out);
}

// Round 15
// 111.792 us; speedup vs baseline: 1.4684x; 1.0630x over previous
//
#include <hip/hip_runtime.h>
#include <hip/hip_fp16.h>

#define LDIM 256
#define NDIM 256
#define DZC  128
#define HN   4
#define DHD  32
#define DCC  128
#define MROWS (LDIM*NDIM)

typedef _Float16 f16;
typedef _Float16 f16x2 __attribute__((ext_vector_type(2)));
typedef _Float16 f16x4 __attribute__((ext_vector_type(4)));
typedef _Float16 f16x8 __attribute__((ext_vector_type(8)));
typedef __fp16   h16x2 __attribute__((ext_vector_type(2)));
typedef float    f32x4 __attribute__((ext_vector_type(4)));

#define SCAL 0.17677669529663687f      // 1/sqrt(32)
#define CEXP -0.011270992135622957f    // -log2(e)/128
#define CPRE 0.2550340490960039f       // SCAL * log2(e)

__device__ inline f16x2 pkrtz(float a, float b){
  h16x2 r = __builtin_amdgcn_cvt_pkrtz(a, b);
  union { h16x2 h; f16x2 f; } u; u.h = r;
  return u.f;
}

// ---------------- K0b: pack W^T f16 — w16[p][col][k] = W_p[k][col] ----------------
__global__ __launch_bounds__(256) void k0b_pack(
    const float* __restrict__ Wq, const float* __restrict__ Wk,
    const float* __restrict__ Wv, const float* __restrict__ Wg,
    const float* __restrict__ Wo, f16* __restrict__ w16)
{
  const float* Ws[5] = {Wq, Wk, Wv, Wg, Wo};
  const int tid = blockIdx.x * 256 + threadIdx.x;
  const int p = tid >> 14, rem = tid & 16383;
  const int col = rem >> 7, k = rem & 127;
  w16[tid] = (f16)Ws[p][k*128 + col];
}

// ---------------- K1: LN + Q/K/V/Gate via MFMA ----------------
__global__ __launch_bounds__(256, 2) void k1_ln_qkvg(
    const float* __restrict__ z, const float* __restrict__ lng, const float* __restrict__ lnb,
    const f16* __restrict__ w16,
    const float* __restrict__ bq, const float* __restrict__ bk,
    const float* __restrict__ bv, const float* __restrict__ bg,
    f16* __restrict__ qb, f16* __restrict__ kbuf,
    f16* __restrict__ vbuf, f16* __restrict__ gateb)
{
  __shared__ f16 zl[64*128];   // 16 KB
  const int t = threadIdx.x;
  const int w = t >> 6, lane = t & 63;
  const int m = lane & 15, g = lane >> 4;
  const int row0 = blockIdx.x * 64;

  {
    const int r = t >> 2, part = t & 3;
    const float* zr = z + (size_t)(row0 + r)*DZC + part*32;
    float vals[32];
    float s = 0.f, sq = 0.f;
    #pragma unroll
    for (int i = 0; i < 8; ++i) {
      float4 v4 = reinterpret_cast<const float4*>(zr)[i];
      vals[i*4+0]=v4.x; vals[i*4+1]=v4.y; vals[i*4+2]=v4.z; vals[i*4+3]=v4.w;
      s  += v4.x+v4.y+v4.z+v4.w;
      sq += v4.x*v4.x + v4.y*v4.y + v4.z*v4.z + v4.w*v4.w;
    }
    s  += __shfl_xor(s, 1);  sq += __shfl_xor(sq, 1);
    s  += __shfl_xor(s, 2);  sq += __shfl_xor(sq, 2);
    const float mu  = s * (1.f/DZC);
    const float var = sq * (1.f/DZC) - mu*mu;
    const float rstd = rsqrtf(var + 1e-5f);
    const float* gg = lng + part*32;
    const float* bb = lnb + part*32;
    #pragma unroll
    for (int i = 0; i < 4; ++i) {
      f16x8 o;
      #pragma unroll
      for (int e = 0; e < 8; ++e)
        o[e] = (f16)((vals[i*8+e]-mu)*rstd*gg[i*8+e] + bb[i*8+e]);
      *reinterpret_cast<f16x8*>(zl + r*128 + (((part*4+i) ^ (r&7))*8)) = o;
    }
  }
  __syncthreads();

  const f16* wp = w16 + w*16384;
  f32x4 acc[4][8];
  #pragma unroll
  for (int it=0;it<4;++it)
    #pragma unroll
    for (int jt=0;jt<8;++jt) acc[it][jt] = (f32x4){0.f,0.f,0.f,0.f};

  #pragma unroll
  for (int ks = 0; ks < 4; ++ks) {
    f16x8 af[8];
    #pragma unroll
    for (int jt=0;jt<8;++jt)
      af[jt] = *reinterpret_cast<const f16x8*>(wp + (jt*16+m)*128 + ks*32 + g*8);
    f16x8 bf[4];
    #pragma unroll
    for (int it=0;it<4;++it)
      bf[it] = *reinterpret_cast<const f16x8*>(zl + (it*16+m)*128 + (((ks*4+g) ^ (m&7))*8));
    #pragma unroll
    for (int it=0;it<4;++it)
      #pragma unroll
      for (int jt=0;jt<8;++jt)
        acc[it][jt] = __builtin_amdgcn_mfma_f32_16x16x32_f16(af[jt], bf[it], acc[it][jt], 0,0,0);
  }

  const float* bsp = (w==0) ? bq : (w==1) ? bk : (w==2) ? bv : bg;
  float4 bias[8];
  #pragma unroll
  for (int jt=0;jt<8;++jt)
    bias[jt] = *reinterpret_cast<const float4*>(bsp + jt*16 + g*4);

  const int l = row0 >> 8, i0 = row0 & 255;
  if (w < 3) {
    f16* ob = (w==0) ? qb : (w==1) ? kbuf : vbuf;
    #pragma unroll
    for (int it=0;it<4;++it) {
      const int i = i0 + it*16 + m;
      #pragma unroll
      for (int jt=0;jt<8;++jt) {
        const int hh = jt >> 1, dh0 = (jt&1)*16 + g*4;
        f16x4 o;
        #pragma unroll
        for (int r=0;r<4;++r) o[r] = (f16)(acc[it][jt][r] + ((const float*)&bias[jt])[r]);
        *reinterpret_cast<f16x4*>(ob + ((size_t)(l*HN + hh)*NDIM + i)*DHD + dh0) = o;
      }
    }
  } else {
    #pragma unroll
    for (int it=0;it<4;++it) {
      const int rowg = row0 + it*16 + m;
      #pragma unroll
      for (int jt=0;jt<8;++jt) {
        f16x4 o;
        #pragma unroll
        for (int r=0;r<4;++r) {
          const float v = acc[it][jt][r] + ((const float*)&bias[jt])[r];
          o[r] = (f16)(1.f/(1.f + __expf(-v)));
        }
        *reinterpret_cast<f16x4*>(gateb + (size_t)rowg*DCC + jt*16 + g*4) = o;
      }
    }
  }
}

// ---------------- K2: rolled jc + f32 cf + pkrtz + ASYNC dist prefetch ----------------
// T14 split: stage si's 4 float4 dist loads are issued during stage si-1's
// compute phase (regs only — no barrier-structure change vs verified R13).
// Evidence: warm-dist run (R10) = 43.8us vs cold 59.3 -> ~16us un-overlapped fetch.
__global__ __launch_bounds__(256, 2) void k2_attn(
    const f16* __restrict__ qb, const f16* __restrict__ kbuf,
    const f16* __restrict__ vbuf, const float* __restrict__ dist,
    f16* __restrict__ zcom)
{
  __shared__ f16 vt[4*32*256];   // 64 KB, per-head swizzled V^T
  __shared__ float cfl[64*64];   // 16 KB f32 coef tile (64 rows)
  const int t = threadIdx.x;
  const int w = t >> 6, lane = t & 63;
  const int m = lane & 15, g = lane >> 4;
  const int orig = blockIdx.x;
  const int swz = (orig & 7)*64 + (orig >> 3);   // bijective XCD swizzle (512%8==0)
  const int l = swz >> 1, half = swz & 1;
  const int r0 = half*128;
  const size_t lb4 = (size_t)l*HN;

  {
    #pragma unroll
    for (int hh = 0; hh < 4; ++hh) {
      const f16x8* vg = reinterpret_cast<const f16x8*>(
          vbuf + (lb4 + hh)*(NDIM*DHD) + (size_t)t*DHD);
      #pragma unroll
      for (int p = 0; p < 4; ++p) {
        f16x8 v = vg[p];
        #pragma unroll
        for (int e = 0; e < 8; ++e) {
          const int c = p*8 + e;
          vt[hh*8192 + c*256 + (((t>>2) ^ (c&15))*4) + (t&3)] = v[e];
        }
      }
    }
  }

  const size_t hb = (lb4 + w) * (NDIM*DHD);
  f16x8 aq[8];
  #pragma unroll
  for (int it = 0; it < 8; ++it)
    aq[it] = *reinterpret_cast<const f16x8*>(qb + hb + (size_t)(r0 + it*16 + m)*DHD + g*8);

  f32x4 o[8][2];
  float rs[8];
  #pragma unroll
  for (int it = 0; it < 8; ++it) {
    o[it][0] = (f32x4){0.f,0.f,0.f,0.f};
    o[it][1] = (f32x4){0.f,0.f,0.f,0.f};
    rs[it] = 0.f;
  }

  const float* drow = dist + (size_t)l*(NDIM*NDIM);
  // per-thread stage-granule geometry (fixed across stages)
  const int prow[4] = { (0*256+t) >> 4, (1*256+t) >> 4, (2*256+t) >> 4, (3*256+t) >> 4 };
  const int pf4 [4] = { t & 15, t & 15, t & 15, t & 15 };  // fi&15 == t&15 for all p

  // prologue: issue stage-0 (jc=0, rh=0) dist loads into regs
  float4 pf[4];
  #pragma unroll
  for (int p = 0; p < 4; ++p)
    pf[p] = *reinterpret_cast<const float4*>(
        drow + (size_t)(r0 + 0*64 + prow[p])*NDIM + 0*64 + pf4[p]*4);

  __syncthreads();   // VT build complete before any wave reads vt (R12 race fix)

  const f16* vth = vt + w*8192;

  #pragma unroll 1
  for (int jc = 0; jc < 4; ++jc) {
    f16x8 kf[4];
    #pragma unroll
    for (int jt = 0; jt < 4; ++jt)
      kf[jt] = *reinterpret_cast<const f16x8*>(
          kbuf + hb + (size_t)(jc*64 + jt*16 + m)*DHD + g*8);

    f16x8 bvv[2][2];
    #pragma unroll
    for (int kc = 0; kc < 2; ++kc)
      #pragma unroll
      for (int ct = 0; ct < 2; ++ct) {
        const int c = ct*16 + m;
        const f16x4 lo = *reinterpret_cast<const f16x4*>(
            vth + c*256 + (((jc*16 + (2*kc+0)*4 + g) ^ m) * 4));
        const f16x4 hi = *reinterpret_cast<const f16x4*>(
            vth + c*256 + (((jc*16 + (2*kc+1)*4 + g) ^ m) * 4));
        f16x8 bb;
        #pragma unroll
        for (int e = 0; e < 4; ++e) { bb[e] = lo[e]; bb[4+e] = hi[e]; }
        bvv[kc][ct] = bb;
      }

    #pragma unroll
    for (int rh = 0; rh < 2; ++rh) {
      __syncthreads();   // prior cfl reads complete
      // consume prefetched regs
      float4 d0 = pf[0], d1 = pf[1], d2 = pf[2], d3 = pf[3];
      // issue NEXT stage's loads (si+1, clamped) — in flight through compute
      {
        const int si1 = jc*2 + rh + 1;
        const int sic = (si1 > 7) ? 7 : si1;
        const int jn = sic >> 1, rn = sic & 1;
        #pragma unroll
        for (int p = 0; p < 4; ++p)
          pf[p] = *reinterpret_cast<const float4*>(
              drow + (size_t)(r0 + rn*64 + prow[p])*NDIM + jn*64 + pf4[p]*4);
      }
      // convert + store cfl
      {
        const float4 dd[4] = {d0, d1, d2, d3};
        #pragma unroll
        for (int p = 0; p < 4; ++p) {
          const int row = prow[p], f4 = pf4[p];
          float4 cf4;
          cf4.x = CPRE * exp2f(dd[p].x*dd[p].x*CEXP);
          cf4.y = CPRE * exp2f(dd[p].y*dd[p].y*CEXP);
          cf4.z = CPRE * exp2f(dd[p].z*dd[p].z*CEXP);
          cf4.w = CPRE * exp2f(dd[p].w*dd[p].w*CEXP);
          *reinterpret_cast<float4*>(cfl + row*64 + ((f4 ^ (row & 15))*4)) = cf4;
        }
      }
      __syncthreads();

      #pragma unroll
      for (int itl = 0; itl < 4; ++itl) {
        const int it = rh*4 + itl;
        const int lr = itl*16 + m;
        float4 cl[4];
        #pragma unroll
        for (int jt = 0; jt < 4; ++jt)
          cl[jt] = *reinterpret_cast<const float4*>(
              cfl + lr*64 + (((jt*4 + g) ^ m)*4));

        f32x4 s[4];
        #pragma unroll
        for (int jt = 0; jt < 4; ++jt)
          s[jt] = __builtin_amdgcn_mfma_f32_16x16x32_f16(
              kf[jt], aq[it], (f32x4){0.f,0.f,0.f,0.f}, 0, 0, 0);

        f16x2 pk[4][2];
        #pragma unroll
        for (int jt = 0; jt < 4; ++jt) {
          const float p0 = exp2f(s[jt][0] * cl[jt].x);
          const float p1 = exp2f(s[jt][1] * cl[jt].y);
          const float p2 = exp2f(s[jt][2] * cl[jt].z);
          const float p3 = exp2f(s[jt][3] * cl[jt].w);
          rs[it] += (p0 + p1) + (p2 + p3);
          pk[jt][0] = pkrtz(p0, p1);
          pk[jt][1] = pkrtz(p2, p3);
        }

        #pragma unroll
        for (int kc = 0; kc < 2; ++kc) {
          const f16x4 x = __builtin_shufflevector(pk[2*kc  ][0], pk[2*kc  ][1], 0,1,2,3);
          const f16x4 y = __builtin_shufflevector(pk[2*kc+1][0], pk[2*kc+1][1], 0,1,2,3);
          const f16x8 ap = __builtin_shufflevector(x, y, 0,1,2,3,4,5,6,7);
          o[it][0] = __builtin_amdgcn_mfma_f32_16x16x32_f16(ap, bvv[kc][0], o[it][0], 0, 0, 0);
          o[it][1] = __builtin_amdgcn_mfma_f32_16x16x32_f16(ap, bvv[kc][1], o[it][1], 0, 0, 0);
        }
      }
    }
  }

  float rinv[8];
  #pragma unroll
  for (int it = 0; it < 8; ++it) {
    float v = rs[it];
    v += __shfl_xor(v, 16);
    v += __shfl_xor(v, 32);
    rinv[it] = 1.f / v;
  }

  #pragma unroll
  for (int it = 0; it < 8; ++it)
    #pragma unroll
    for (int r = 0; r < 4; ++r) {
      const float rr = __shfl(rinv[it], (lane & 48) + g*4 + r);
      const int row = l*NDIM + r0 + it*16 + g*4 + r;
      #pragma unroll
      for (int ct = 0; ct < 2; ++ct) {
        const int col = w*DHD + ct*16 + m;
        zcom[(size_t)row*DCC + col] = (f16)(o[it][ct][r] * rr);
      }
    }
}

// ---------------- K3: gated output projection via MFMA ----------------
__global__ __launch_bounds__(256, 4) void k3_out(
    const f16* __restrict__ zcom, const f16* __restrict__ gateb,
    const f16* __restrict__ wo16, const float* __restrict__ bo,
    float* __restrict__ out)
{
  const int t = threadIdx.x;
  const int w = t >> 6, lane = t & 63;
  const int m = lane & 15, g = lane >> 4;
  const size_t row = blockIdx.x*64 + w*16 + m;

  f32x4 acc[8];
  #pragma unroll
  for (int jt=0;jt<8;++jt) acc[jt] = (f32x4){0.f,0.f,0.f,0.f};

  #pragma unroll
  for (int ks = 0; ks < 4; ++ks) {
    f16x8 af[8];
    #pragma unroll
    for (int jt=0;jt<8;++jt)
      af[jt] = *reinterpret_cast<const f16x8*>(wo16 + (jt*16+m)*128 + ks*32 + g*8);
    f16x8 bf = *reinterpret_cast<const f16x8*>(zcom  + row*DCC + ks*32 + g*8);
    f16x8 gf = *reinterpret_cast<const f16x8*>(gateb + row*DCC + ks*32 + g*8);
    bf = bf * gf;
    #pragma unroll
    for (int jt=0;jt<8;++jt)
      acc[jt] = __builtin_amdgcn_mfma_f32_16x16x32_f16(af[jt], bf, acc[jt], 0,0,0);
  }

  #pragma unroll
  for (int jt=0;jt<8;++jt) {
    const float4 bias = *reinterpret_cast<const float4*>(bo + jt*16 + g*4);
    float4 o;
    o.x = acc[jt][0] + bias.x;
    o.y = acc[jt][1] + bias.y;
    o.z = acc[jt][2] + bias.z;
    o.w = acc[jt][3] + bias.w;
    *reinterpret_cast<float4*>(out + row*DZC + jt*16 + g*4) = o;
  }
}

extern "C" void kernel_launch(void* const* d_in, const int* in_sizes, int n_in,
                              void* d_out, int out_size, void* d_ws, size_t ws_size,
                              hipStream_t stream) {
  const float* z    = (const float*)d_in[0];
  const float* dist = (const float*)d_in[1];
  const float* lng  = (const float*)d_in[2];
  const float* lnb  = (const float*)d_in[3];
  const float* Wq   = (const float*)d_in[4];
  const float* bq   = (const float*)d_in[5];
  const float* Wk   = (const float*)d_in[6];
  const float* bk   = (const float*)d_in[7];
  const float* Wv   = (const float*)d_in[8];
  const float* bv   = (const float*)d_in[9];
  const float* Wg   = (const float*)d_in[10];
  const float* bg   = (const float*)d_in[11];
  const float* Wo   = (const float*)d_in[12];
  const float* bo   = (const float*)d_in[13];
  float* out = (float*)d_out;

  const size_t elems = (size_t)MROWS * DCC;  // 8,388,608
  f16* qb    = (f16*)d_ws;
  f16* kbuf  = qb    + elems;
  f16* vbuf  = kbuf  + elems;
  f16* gateb = vbuf  + elems;
  f16* zcom  = gateb + elems;
  f16* w16   = zcom  + elems;   // 5*16384 halves; total ws ≈ 84 MB

  k0b_pack<<<320, 256, 0, stream>>>(Wq, Wk, Wv, Wg, Wo, w16);
  k1_ln_qkvg<<<MROWS/64, 256, 0, stream>>>(z, lng, lnb, w16, bq, bk, bv, bg,
                                           qb, kbuf, vbuf, gateb);
  k2_attn<<<LDIM*2, 256, 0, stream>>>(qb, kbuf, vbuf, dist, zcom);
  k3_out<<<MROWS/64, 256, 0, stream>>>(zcom, gateb, w16 + 4*16384, bo, out);
}

// Round 16
// 104.505 us; speedup vs baseline: 1.5707x; 1.0697x over previous
//
#include <hip/hip_runtime.h>
#include <hip/hip_fp16.h>

#define LDIM 256
#define NDIM 256
#define DZC  128
#define HN   4
#define DHD  32
#define DCC  128
#define MROWS (LDIM*NDIM)

typedef _Float16 f16;
typedef _Float16 f16x2 __attribute__((ext_vector_type(2)));
typedef _Float16 f16x4 __attribute__((ext_vector_type(4)));
typedef _Float16 f16x8 __attribute__((ext_vector_type(8)));
typedef __fp16   h16x2 __attribute__((ext_vector_type(2)));
typedef float    f32x4 __attribute__((ext_vector_type(4)));

#define SCAL 0.17677669529663687f      // 1/sqrt(32)
#define CEXP -0.011270992135622957f    // -log2(e)/128
#define CPRE 0.2550340490960039f       // SCAL * log2(e)

__device__ inline f16x2 pkrtz(float a, float b){
  h16x2 r = __builtin_amdgcn_cvt_pkrtz(a, b);
  union { h16x2 h; f16x2 f; } u; u.h = r;
  return u.f;
}

// ---------------- K0b: pack W^T f16 — w16[p][col][k] = W_p[k][col] ----------------
__global__ __launch_bounds__(256) void k0b_pack(
    const float* __restrict__ Wq, const float* __restrict__ Wk,
    const float* __restrict__ Wv, const float* __restrict__ Wg,
    const float* __restrict__ Wo, f16* __restrict__ w16)
{
  const float* Ws[5] = {Wq, Wk, Wv, Wg, Wo};
  const int tid = blockIdx.x * 256 + threadIdx.x;
  const int p = tid >> 14, rem = tid & 16383;
  const int col = rem >> 7, k = rem & 127;
  w16[tid] = (f16)Ws[p][k*128 + col];
}

// ---------------- K1: LN + Q/K/V/Gate via MFMA ----------------
// All four outputs ROW-MAJOR [65536][128]: epilogue = 1 base addr per it,
// 8 stores at static offsets (kills per-store address math of head-major).
__global__ __launch_bounds__(256, 2) void k1_ln_qkvg(
    const float* __restrict__ z, const float* __restrict__ lng, const float* __restrict__ lnb,
    const f16* __restrict__ w16,
    const float* __restrict__ bq, const float* __restrict__ bk,
    const float* __restrict__ bv, const float* __restrict__ bg,
    f16* __restrict__ qb, f16* __restrict__ kbuf,
    f16* __restrict__ vbuf, f16* __restrict__ gateb)
{
  __shared__ f16 zl[64*128];   // 16 KB
  const int t = threadIdx.x;
  const int w = t >> 6, lane = t & 63;
  const int m = lane & 15, g = lane >> 4;
  const int row0 = blockIdx.x * 64;

  {
    const int r = t >> 2, part = t & 3;
    const float* zr = z + (size_t)(row0 + r)*DZC + part*32;
    float vals[32];
    float s = 0.f, sq = 0.f;
    #pragma unroll
    for (int i = 0; i < 8; ++i) {
      float4 v4 = reinterpret_cast<const float4*>(zr)[i];
      vals[i*4+0]=v4.x; vals[i*4+1]=v4.y; vals[i*4+2]=v4.z; vals[i*4+3]=v4.w;
      s  += v4.x+v4.y+v4.z+v4.w;
      sq += v4.x*v4.x + v4.y*v4.y + v4.z*v4.z + v4.w*v4.w;
    }
    s  += __shfl_xor(s, 1);  sq += __shfl_xor(sq, 1);
    s  += __shfl_xor(s, 2);  sq += __shfl_xor(sq, 2);
    const float mu  = s * (1.f/DZC);
    const float var = sq * (1.f/DZC) - mu*mu;
    const float rstd = rsqrtf(var + 1e-5f);
    const float* gg = lng + part*32;
    const float* bb = lnb + part*32;
    #pragma unroll
    for (int i = 0; i < 4; ++i) {
      f16x8 o;
      #pragma unroll
      for (int e = 0; e < 8; ++e)
        o[e] = (f16)((vals[i*8+e]-mu)*rstd*gg[i*8+e] + bb[i*8+e]);
      *reinterpret_cast<f16x8*>(zl + r*128 + (((part*4+i) ^ (r&7))*8)) = o;
    }
  }
  __syncthreads();

  const f16* wp = w16 + w*16384;
  f32x4 acc[4][8];
  #pragma unroll
  for (int it=0;it<4;++it)
    #pragma unroll
    for (int jt=0;jt<8;++jt) acc[it][jt] = (f32x4){0.f,0.f,0.f,0.f};

  #pragma unroll
  for (int ks = 0; ks < 4; ++ks) {
    f16x8 af[8];
    #pragma unroll
    for (int jt=0;jt<8;++jt)
      af[jt] = *reinterpret_cast<const f16x8*>(wp + (jt*16+m)*128 + ks*32 + g*8);
    f16x8 bf[4];
    #pragma unroll
    for (int it=0;it<4;++it)
      bf[it] = *reinterpret_cast<const f16x8*>(zl + (it*16+m)*128 + (((ks*4+g) ^ (m&7))*8));
    #pragma unroll
    for (int it=0;it<4;++it)
      #pragma unroll
      for (int jt=0;jt<8;++jt)
        acc[it][jt] = __builtin_amdgcn_mfma_f32_16x16x32_f16(af[jt], bf[it], acc[it][jt], 0,0,0);
  }

  const float* bsp = (w==0) ? bq : (w==1) ? bk : (w==2) ? bv : bg;
  float4 bias[8];
  #pragma unroll
  for (int jt=0;jt<8;++jt)
    bias[jt] = *reinterpret_cast<const float4*>(bsp + jt*16 + g*4);

  f16* ob = (w==0) ? qb : (w==1) ? kbuf : (w==2) ? vbuf : gateb;
  #pragma unroll
  for (int it=0;it<4;++it) {
    f16* orow = ob + (size_t)(row0 + it*16 + m)*DCC;
    #pragma unroll
    for (int jt=0;jt<8;++jt) {
      f16x4 o;
      #pragma unroll
      for (int r=0;r<4;++r) {
        float v = acc[it][jt][r] + ((const float*)&bias[jt])[r];
        if (w == 3) v = 1.f/(1.f + __expf(-v));
        o[r] = (f16)v;
      }
      *reinterpret_cast<f16x4*>(orow + jt*16 + g*4) = o;
    }
  }
}

// ---------------- K2: fused attention + output projection ----------------
// R14 winner (rolled jc + f32 cf + pkrtz + async dist prefetch) + fused k3:
// block (l,half) holds full z_com[128][128] across its 4 waves -> LDS (reuse
// vt as zc[128][132]), barrier, per-wave 32-row mini-GEMM with Wo (gate on
// B-frag, bias, fp32 out). Deletes the 33.6MB zcom round-trip + k3 launch.
__global__ __launch_bounds__(256, 2) void k2_attn(
    const f16* __restrict__ qb, const f16* __restrict__ kbuf,
    const f16* __restrict__ vbuf, const f16* __restrict__ gateb,
    const float* __restrict__ dist, const f16* __restrict__ wo16,
    const float* __restrict__ bo, float* __restrict__ out)
{
  __shared__ f16 vt[4*32*256];   // 64 KB V^T; reused as zc[128][132] in epilogue
  __shared__ float cfl[64*64];   // 16 KB f32 coef tile (64 rows)
  const int t = threadIdx.x;
  const int w = t >> 6, lane = t & 63;
  const int m = lane & 15, g = lane >> 4;
  const int orig = blockIdx.x;
  const int swz = (orig & 7)*64 + (orig >> 3);   // bijective XCD swizzle (512%8==0)
  const int l = swz >> 1, half = swz & 1;
  const int r0 = half*128;
  const int lrow0 = l*NDIM;

  { // build VT from row-major vbuf
    #pragma unroll
    for (int hh = 0; hh < 4; ++hh) {
      const f16* vr = vbuf + (size_t)(lrow0 + t)*DCC + hh*DHD;
      #pragma unroll
      for (int p = 0; p < 4; ++p) {
        f16x8 v = *reinterpret_cast<const f16x8*>(vr + p*8);
        #pragma unroll
        for (int e = 0; e < 8; ++e) {
          const int c = p*8 + e;
          vt[hh*8192 + c*256 + (((t>>2) ^ (c&15))*4) + (t&3)] = v[e];
        }
      }
    }
  }

  f16x8 aq[8];
  #pragma unroll
  for (int it = 0; it < 8; ++it)
    aq[it] = *reinterpret_cast<const f16x8*>(
        qb + (size_t)(lrow0 + r0 + it*16 + m)*DCC + w*DHD + g*8);

  f32x4 o[8][2];
  float rs[8];
  #pragma unroll
  for (int it = 0; it < 8; ++it) {
    o[it][0] = (f32x4){0.f,0.f,0.f,0.f};
    o[it][1] = (f32x4){0.f,0.f,0.f,0.f};
    rs[it] = 0.f;
  }

  const float* drow = dist + (size_t)l*(NDIM*NDIM);
  const int prow[4] = { (0*256+t) >> 4, (1*256+t) >> 4, (2*256+t) >> 4, (3*256+t) >> 4 };
  const int pf4  = t & 15;

  // prologue: issue stage-0 (jc=0, rh=0) dist loads into regs
  float4 pf[4];
  #pragma unroll
  for (int p = 0; p < 4; ++p)
    pf[p] = *reinterpret_cast<const float4*>(
        drow + (size_t)(r0 + prow[p])*NDIM + pf4*4);

  __syncthreads();   // VT build complete before any wave reads vt

  const f16* vth = vt + w*8192;

  #pragma unroll 1
  for (int jc = 0; jc < 4; ++jc) {
    f16x8 kf[4];
    #pragma unroll
    for (int jt = 0; jt < 4; ++jt)
      kf[jt] = *reinterpret_cast<const f16x8*>(
          kbuf + (size_t)(lrow0 + jc*64 + jt*16 + m)*DCC + w*DHD + g*8);

    f16x8 bvv[2][2];
    #pragma unroll
    for (int kc = 0; kc < 2; ++kc)
      #pragma unroll
      for (int ct = 0; ct < 2; ++ct) {
        const int c = ct*16 + m;
        const f16x4 lo = *reinterpret_cast<const f16x4*>(
            vth + c*256 + (((jc*16 + (2*kc+0)*4 + g) ^ m) * 4));
        const f16x4 hi = *reinterpret_cast<const f16x4*>(
            vth + c*256 + (((jc*16 + (2*kc+1)*4 + g) ^ m) * 4));
        f16x8 bb;
        #pragma unroll
        for (int e = 0; e < 4; ++e) { bb[e] = lo[e]; bb[4+e] = hi[e]; }
        bvv[kc][ct] = bb;
      }

    #pragma unroll
    for (int rh = 0; rh < 2; ++rh) {
      __syncthreads();   // prior cfl reads complete
      float4 d0 = pf[0], d1 = pf[1], d2 = pf[2], d3 = pf[3];
      { // issue NEXT stage's loads — in flight through compute
        const int si1 = jc*2 + rh + 1;
        const int sic = (si1 > 7) ? 7 : si1;
        const int jn = sic >> 1, rn = sic & 1;
        #pragma unroll
        for (int p = 0; p < 4; ++p)
          pf[p] = *reinterpret_cast<const float4*>(
              drow + (size_t)(r0 + rn*64 + prow[p])*NDIM + jn*64 + pf4*4);
      }
      {
        const float4 dd[4] = {d0, d1, d2, d3};
        #pragma unroll
        for (int p = 0; p < 4; ++p) {
          const int row = prow[p];
          float4 cf4;
          cf4.x = CPRE * exp2f(dd[p].x*dd[p].x*CEXP);
          cf4.y = CPRE * exp2f(dd[p].y*dd[p].y*CEXP);
          cf4.z = CPRE * exp2f(dd[p].z*dd[p].z*CEXP);
          cf4.w = CPRE * exp2f(dd[p].w*dd[p].w*CEXP);
          *reinterpret_cast<float4*>(cfl + row*64 + ((pf4 ^ (row & 15))*4)) = cf4;
        }
      }
      __syncthreads();

      #pragma unroll
      for (int itl = 0; itl < 4; ++itl) {
        const int it = rh*4 + itl;
        const int lr = itl*16 + m;
        float4 cl[4];
        #pragma unroll
        for (int jt = 0; jt < 4; ++jt)
          cl[jt] = *reinterpret_cast<const float4*>(
              cfl + lr*64 + (((jt*4 + g) ^ m)*4));

        f32x4 s[4];
        #pragma unroll
        for (int jt = 0; jt < 4; ++jt)
          s[jt] = __builtin_amdgcn_mfma_f32_16x16x32_f16(
              kf[jt], aq[it], (f32x4){0.f,0.f,0.f,0.f}, 0, 0, 0);

        f16x2 pk[4][2];
        #pragma unroll
        for (int jt = 0; jt < 4; ++jt) {
          const float p0 = exp2f(s[jt][0] * cl[jt].x);
          const float p1 = exp2f(s[jt][1] * cl[jt].y);
          const float p2 = exp2f(s[jt][2] * cl[jt].z);
          const float p3 = exp2f(s[jt][3] * cl[jt].w);
          rs[it] += (p0 + p1) + (p2 + p3);
          pk[jt][0] = pkrtz(p0, p1);
          pk[jt][1] = pkrtz(p2, p3);
        }

        #pragma unroll
        for (int kc = 0; kc < 2; ++kc) {
          const f16x4 x = __builtin_shufflevector(pk[2*kc  ][0], pk[2*kc  ][1], 0,1,2,3);
          const f16x4 y = __builtin_shufflevector(pk[2*kc+1][0], pk[2*kc+1][1], 0,1,2,3);
          const f16x8 ap = __builtin_shufflevector(x, y, 0,1,2,3,4,5,6,7);
          o[it][0] = __builtin_amdgcn_mfma_f32_16x16x32_f16(ap, bvv[kc][0], o[it][0], 0, 0, 0);
          o[it][1] = __builtin_amdgcn_mfma_f32_16x16x32_f16(ap, bvv[kc][1], o[it][1], 0, 0, 0);
        }
      }
    }
  }

  float rinv[8];
  #pragma unroll
  for (int it = 0; it < 8; ++it) {
    float v = rs[it];
    v += __shfl_xor(v, 16);
    v += __shfl_xor(v, 32);
    rinv[it] = 1.f / v;
  }

  // ---- fused epilogue: z_com -> LDS, then out = (zc*gate) @ Wo + bo ----
  __syncthreads();   // all waves done reading vt (jc=3 bvv)
  f16* zc = vt;      // [128][132]: write banks conflict-free, b64 reads ~4-way
  #pragma unroll
  for (int it = 0; it < 8; ++it)
    #pragma unroll
    for (int r = 0; r < 4; ++r) {
      const float rr = __shfl(rinv[it], (lane & 48) + g*4 + r);
      const int lrow = it*16 + g*4 + r;
      #pragma unroll
      for (int ct = 0; ct < 2; ++ct)
        zc[lrow*132 + w*DHD + ct*16 + m] = (f16)(o[it][ct][r] * rr);
    }
  __syncthreads();

  f32x4 acc2[2][8];
  #pragma unroll
  for (int it2=0;it2<2;++it2)
    #pragma unroll
    for (int jt=0;jt<8;++jt) acc2[it2][jt] = (f32x4){0.f,0.f,0.f,0.f};

  #pragma unroll
  for (int ks = 0; ks < 4; ++ks) {
    f16x8 af[8];
    #pragma unroll
    for (int jt=0;jt<8;++jt)
      af[jt] = *reinterpret_cast<const f16x8*>(wo16 + (jt*16+m)*128 + ks*32 + g*8);
    f16x8 bf[2];
    #pragma unroll
    for (int it2 = 0; it2 < 2; ++it2) {
      const int lrow = w*32 + it2*16 + m;
      const f16x4 b0 = *reinterpret_cast<const f16x4*>(zc + lrow*132 + ks*32 + g*8);
      const f16x4 b1 = *reinterpret_cast<const f16x4*>(zc + lrow*132 + ks*32 + g*8 + 4);
      const f16x8 zf = __builtin_shufflevector(b0, b1, 0,1,2,3,4,5,6,7);
      const f16x8 gf = *reinterpret_cast<const f16x8*>(
          gateb + (size_t)(lrow0 + r0 + lrow)*DCC + ks*32 + g*8);
      bf[it2] = zf * gf;
    }
    #pragma unroll
    for (int it2=0;it2<2;++it2)
      #pragma unroll
      for (int jt=0;jt<8;++jt)
        acc2[it2][jt] = __builtin_amdgcn_mfma_f32_16x16x32_f16(af[jt], bf[it2], acc2[it2][jt], 0,0,0);
  }

  #pragma unroll
  for (int it2 = 0; it2 < 2; ++it2) {
    const size_t grow = (size_t)(lrow0 + r0 + w*32 + it2*16 + m);
    #pragma unroll
    for (int jt = 0; jt < 8; ++jt) {
      const float4 bias = *reinterpret_cast<const float4*>(bo + jt*16 + g*4);
      float4 ov;
      ov.x = acc2[it2][jt][0] + bias.x;
      ov.y = acc2[it2][jt][1] + bias.y;
      ov.z = acc2[it2][jt][2] + bias.z;
      ov.w = acc2[it2][jt][3] + bias.w;
      *reinterpret_cast<float4*>(out + grow*DZC + jt*16 + g*4) = ov;
    }
  }
}

extern "C" void kernel_launch(void* const* d_in, const int* in_sizes, int n_in,
                              void* d_out, int out_size, void* d_ws, size_t ws_size,
                              hipStream_t stream) {
  const float* z    = (const float*)d_in[0];
  const float* dist = (const float*)d_in[1];
  const float* lng  = (const float*)d_in[2];
  const float* lnb  = (const float*)d_in[3];
  const float* Wq   = (const float*)d_in[4];
  const float* bq   = (const float*)d_in[5];
  const float* Wk   = (const float*)d_in[6];
  const float* bk   = (const float*)d_in[7];
  const float* Wv   = (const float*)d_in[8];
  const float* bv   = (const float*)d_in[9];
  const float* Wg   = (const float*)d_in[10];
  const float* bg   = (const float*)d_in[11];
  const float* Wo   = (const float*)d_in[12];
  const float* bo   = (const float*)d_in[13];
  float* out = (float*)d_out;

  const size_t elems = (size_t)MROWS * DCC;  // 8,388,608
  f16* qb    = (f16*)d_ws;
  f16* kbuf  = qb    + elems;
  f16* vbuf  = kbuf  + elems;
  f16* gateb = vbuf  + elems;
  f16* w16   = gateb + elems;   // 5*16384 halves; total ws ≈ 67 MB

  k0b_pack<<<320, 256, 0, stream>>>(Wq, Wk, Wv, Wg, Wo, w16);
  k1_ln_qkvg<<<MROWS/64, 256, 0, stream>>>(z, lng, lnb, w16, bq, bk, bv, bg,
                                           qb, kbuf, vbuf, gateb);
  k2_attn<<<LDIM*2, 256, 0, stream>>>(qb, kbuf, vbuf, gateb, dist,
                                      w16 + 4*16384, bo, out);
}